// Round 4
// baseline (897.419 us; speedup 1.0000x reference)
//
#include <hip/hip_runtime.h>
#include <hip/hip_bf16.h>
#include <cstdint>

// B=32,C=32,V=1024,L=13; 3 supports x order 2; C_IN=224, C_OUT=64.
//  T-arena (in d_out): 4 blocks of [n2=(b,l,c), v] bf16 (x-T, h1-T s=0..2)
//  Ht (ws): [m=(b*1024+v)*13+l, cc=224] bf16 -- cc-contiguous for final MFMA
//  k_prep: x -> T block0 rows + Ht cc0..31 (fused transpose, one LDS tile)
//  k_gemm: C[n2,w]=sum_v X[n2,v]*AT[w,v]; LDS-FREE K-loop: frags loaded
//          direct global->VGPR (64B-granule aligned), no barriers in loop.
//  k_fc:   y[m,o]=sum_cc Ht[m,cc]*W[o,cc]+bias; fully LDS-free, direct
//          f32x4 stores (C-layout == contiguous y granules).

#define SZE 13631488ull        // elems per [13312,1024] block
#define OFF_AT  190840832ull   // Ht bytes = 425984*224*2
#define OFF_WB  197132288ull   // OFF_AT + 3*1024*1024*2
#define WS_NEED 197160960ull   // OFF_WB + 64*224*2

typedef __attribute__((ext_vector_type(8))) short short8;
typedef __attribute__((ext_vector_type(4))) float f32x4;

__device__ __forceinline__ unsigned short f2b(float f) {
    unsigned int u = __builtin_bit_cast(unsigned int, f);
    u += 0x7FFFu + ((u >> 16) & 1u);          // round-to-nearest-even
    return (unsigned short)(u >> 16);
}

// ---------- fused prep: x[b,c,v,l] f32 -> T rows (block0) + Ht cc0..31 ----------
__global__ __launch_bounds__(256) void k_prep(const float* __restrict__ x,
                                              unsigned short* __restrict__ T,
                                              unsigned short* __restrict__ Ht) {
    __shared__ unsigned short sb[32 * 840];   // [c][e=v*13+l], 832 padded to 840
    const int b = blockIdx.x >> 4, vc = blockIdx.x & 15;
    const int t = threadIdx.x;
    const float4* xb = (const float4*)x;
    for (int it = 0; it < 26; ++it) {
        int q = it * 256 + t;                 // 6656 = 32c * 208f4
        int c = q / 208, f = q - c * 208;
        float4 u = xb[(size_t)(b * 32 + c) * 3328 + vc * 208 + f];
        ushort4 pk; pk.x = f2b(u.x); pk.y = f2b(u.y); pk.z = f2b(u.z); pk.w = f2b(u.w);
        *(ushort4*)(sb + c * 840 + f * 4) = pk;
    }
    __syncthreads();
    // T rows  T[(b*13+l)*32+c][vc*64 + 0..63]
    unsigned short* Tb = T + (size_t)b * 13 * 32 * 1024 + (size_t)vc * 64;
    for (int it = 0; it < 26; ++it) {
        int q = it * 256 + t;                 // 6656 = 13l * 32c * 16sg
        int l = q >> 9, r = q & 511, c = r >> 4, sg = r & 15;
        const unsigned short* src = sb + c * 840 + l;
        ushort4 pk;
        pk.x = src[(sg * 4 + 0) * 13];
        pk.y = src[(sg * 4 + 1) * 13];
        pk.z = src[(sg * 4 + 2) * 13];
        pk.w = src[(sg * 4 + 3) * 13];
        *(ushort4*)(Tb + (size_t)(l * 32 + c) * 1024 + sg * 4) = pk;
    }
    // Ht rows  Ht[b*13312 + (vc*64+v)*13 + l][0..31]
    unsigned short* Hb = Ht + ((size_t)b * 13312 + (size_t)vc * 832) * 224;
    for (int it = 0; it < 26; ++it) {
        int q = it * 256 + t;                 // 6656 = 64v * 13l * 8cs
        int v = q / 104, r = q - v * 104, l = r >> 3, cs = r & 7;
        const unsigned short* src = sb + v * 13 + l;
        ushort4 pk;
        pk.x = src[(cs * 4 + 0) * 840];
        pk.y = src[(cs * 4 + 1) * 840];
        pk.z = src[(cs * 4 + 2) * 840];
        pk.w = src[(cs * 4 + 3) * 840];
        *(ushort4*)(Hb + (size_t)(v * 13 + l) * 224 + cs * 4) = pk;
    }
}

// ---------- prep A: A[v,w] f32 -> AT[w,v] bf16, 3 mats ----------
__global__ __launch_bounds__(256) void k_prep_A(const float* __restrict__ A0,
                                                const float* __restrict__ A1,
                                                const float* __restrict__ A2,
                                                unsigned short* __restrict__ AT) {
    const float* A = blockIdx.z == 0 ? A0 : blockIdx.z == 1 ? A1 : A2;
    unsigned short* D = AT + (size_t)blockIdx.z * 1024 * 1024;
    __shared__ float tile[32][33];
    int v0 = blockIdx.y * 32, w0 = blockIdx.x * 32;
    int c = threadIdx.x & 31, r = threadIdx.x >> 5;
    for (int p = 0; p < 4; ++p) {
        int rr = r + p * 8;
        tile[rr][c] = A[(size_t)(v0 + rr) * 1024 + w0 + c];
    }
    __syncthreads();
    for (int p = 0; p < 4; ++p) {
        int rr = r + p * 8;
        D[(size_t)(w0 + rr) * 1024 + v0 + c] = f2b(tile[c][rr]);
    }
}

// ---------- prep W: W[o,cc] f32 -> Wb[o,cc] bf16 ----------
__global__ __launch_bounds__(256) void k_prep_W(const float* __restrict__ W,
                                                unsigned short* __restrict__ Wb) {
    int idx = blockIdx.x * 256 + threadIdx.x;  // 14336 = 56*256
    Wb[idx] = f2b(W[idx]);
}

// ---------- hop GEMM: C[n2,w] = sum_v X[n2,v]*P[w,v], LDS-free K-loop ----------
__global__ __launch_bounds__(256) void k_gemm(const unsigned short* __restrict__ Xb, long xz,
                                              const unsigned short* __restrict__ Pb,
                                              unsigned short* __restrict__ Tout, long tz,
                                              unsigned short* __restrict__ Ht, int cc0b,
                                              int doT) {
    __shared__ union {
        unsigned short cs[128 * 132];         // [n][v], stride 132 (bank spread)
        unsigned short ct[128 * 136];         // [v][n] for Ht write
    } lds;
    const int z = blockIdx.z;
    const unsigned short* X = Xb + (size_t)z * (size_t)xz;
    const unsigned short* P = Pb + (size_t)z * (1024u * 1024u);
    const int i0 = blockIdx.x * 128;          // n2
    const int j0 = blockIdx.y * 128;          // w
    const int t = threadIdx.x;
    const int lane = t & 63, wave = t >> 6;
    const int l16 = lane & 15, quad = lane >> 4;
    const int wi = (wave >> 1) * 64, wj = (wave & 1) * 64;

    const unsigned short* xr[4];
    const unsigned short* pr[4];
#pragma unroll
    for (int mi = 0; mi < 4; ++mi)
        xr[mi] = X + (size_t)(i0 + wi + mi * 16 + l16) * 1024 + quad * 8;
#pragma unroll
    for (int nj = 0; nj < 4; ++nj)
        pr[nj] = P + (size_t)(j0 + wj + nj * 16 + l16) * 1024 + quad * 8;

    f32x4 acc[4][4] = {};
    short8 a[2][4], b[2][4];
#pragma unroll
    for (int mi = 0; mi < 4; ++mi) a[0][mi] = *(const short8*)(xr[mi]);
#pragma unroll
    for (int nj = 0; nj < 4; ++nj) b[0][nj] = *(const short8*)(pr[nj]);

#pragma unroll
    for (int kf = 0; kf < 32; ++kf) {
        const int cur = kf & 1, nxt = cur ^ 1;
        if (kf < 31) {
            const int k = (kf + 1) * 32;      // shorts; byte offset <= 1984 (imm-able)
#pragma unroll
            for (int mi = 0; mi < 4; ++mi) a[nxt][mi] = *(const short8*)(xr[mi] + k);
#pragma unroll
            for (int nj = 0; nj < 4; ++nj) b[nxt][nj] = *(const short8*)(pr[nj] + k);
        }
#pragma unroll
        for (int mi = 0; mi < 4; ++mi)
#pragma unroll
            for (int nj = 0; nj < 4; ++nj)
                acc[mi][nj] = __builtin_amdgcn_mfma_f32_16x16x32_bf16(a[cur][mi], b[cur][nj],
                                                                      acc[mi][nj], 0, 0, 0);
    }

    // ---- epilogue A: [n2, v] write for hop-2 consumption (hop1 only) ----
    if (doT) {
#pragma unroll
        for (int mi = 0; mi < 4; ++mi)
#pragma unroll
            for (int nj = 0; nj < 4; ++nj)
#pragma unroll
                for (int r = 0; r < 4; ++r)
                    lds.cs[(wi + mi * 16 + quad * 4 + r) * 132 + (wj + nj * 16 + l16)] =
                        f2b(acc[mi][nj][r]);
        __syncthreads();
        unsigned short* O = Tout + (size_t)z * (size_t)tz;
#pragma unroll
        for (int rep = 0; rep < 8; ++rep) {
            int q = rep * 256 + t;            // 2048 16B chunks: 128 rows x 16
            int rr = q >> 4, sg = q & 15;
            *(uint4*)(O + (size_t)(i0 + rr) * 1024 + j0 + sg * 8) =
                *(const uint4*)(lds.cs + rr * 132 + sg * 8);
        }
        __syncthreads();
    }

    // ---- epilogue B: transposed stage [v][n], write Ht c-slices ----
#pragma unroll
    for (int mi = 0; mi < 4; ++mi)
#pragma unroll
        for (int nj = 0; nj < 4; ++nj) {
            ushort4 pk;
            pk.x = f2b(acc[mi][nj][0]);
            pk.y = f2b(acc[mi][nj][1]);
            pk.z = f2b(acc[mi][nj][2]);
            pk.w = f2b(acc[mi][nj][3]);
            *(ushort4*)(lds.ct + (wj + nj * 16 + l16) * 136 + wi + mi * 16 + quad * 4) = pk;
        }
    __syncthreads();
    const int cc0 = cc0b + 64 * z;
#pragma unroll
    for (int it = 0; it < 8; ++it) {
        int q = it * 256 + t;                 // 2048 16B chunks: 4 slabs x 128 v x 4 seg
        int sg = q & 3, v = (q >> 2) & 127, s = q >> 9;
        int p = (i0 >> 5) + s;                // slab = b*13 + l
        int b = p / 13, l = p - b * 13;
        size_t m = (size_t)b * 13312 + (size_t)(j0 + v) * 13 + l;
        *(uint4*)(Ht + m * 224 + cc0 + sg * 8) =
            *(const uint4*)(lds.ct + v * 136 + s * 32 + sg * 8);
    }
}

// ---------- final conv: y[m,o] = sum_cc Ht[m,cc]*W[o,cc] + bias ----------
// Fully LDS-free, barrier-free: A and W frags direct from global; acc -> y direct.
__global__ __launch_bounds__(256) void k_fc(const unsigned short* __restrict__ Ht,
                                            const unsigned short* __restrict__ Wb,
                                            const float* __restrict__ bias,
                                            float* __restrict__ y) {
    const int bid = blockIdx.x;
    const int b = bid >> 6, v0 = (bid & 63) * 16;
    const size_t m0 = (size_t)b * 13312 + (size_t)v0 * 13;
    const int t = threadIdx.x;
    const int lane = t & 63, wave = t >> 6;
    const int l16 = lane & 15, quad = lane >> 4;
    const int oc = wave * 16 + l16;           // this lane's output column

    const unsigned short* hb = Ht + (m0 + l16) * 224 + quad * 8;
    const unsigned short* wb = Wb + (size_t)oc * 224 + quad * 8;
    float bv = bias[oc];
    f32x4 acc[13];
#pragma unroll
    for (int mf = 0; mf < 13; ++mf) acc[mf] = (f32x4){bv, bv, bv, bv};

#pragma unroll
    for (int kk = 0; kk < 7; ++kk) {
        short8 wf = *(const short8*)(wb + kk * 32);
#pragma unroll
        for (int mf = 0; mf < 13; ++mf) {
            short8 hf = *(const short8*)(hb + (size_t)mf * 16 * 224 + kk * 32);
            acc[mf] = __builtin_amdgcn_mfma_f32_16x16x32_bf16(hf, wf, acc[mf], 0, 0, 0);
        }
    }
    // store: lane holds C rows quad*4+r (r=0..3) of col oc; y row-contig in m
    float* yb = y + (size_t)b * 851968 + (size_t)oc * 13312 + (size_t)v0 * 13 + quad * 4;
#pragma unroll
    for (int mf = 0; mf < 13; ++mf)
        *(f32x4*)(yb + mf * 16) = acc[mf];
}

extern "C" void kernel_launch(void* const* d_in, const int* in_sizes, int n_in,
                              void* d_out, int out_size, void* d_ws, size_t ws_size,
                              hipStream_t stream) {
    const float* x    = (const float*)d_in[0];
    const float* A0   = (const float*)d_in[1];
    const float* A1   = (const float*)d_in[2];
    const float* A2   = (const float*)d_in[3];
    const float* W    = (const float*)d_in[4];
    const float* bias = (const float*)d_in[5];

    if (ws_size < WS_NEED) return;

    unsigned short* Ht = (unsigned short*)d_ws;
    unsigned short* AT = (unsigned short*)((char*)d_ws + OFF_AT);
    unsigned short* Wb = (unsigned short*)((char*)d_ws + OFF_WB);
    unsigned short* Tarena = (unsigned short*)d_out;   // 4 x SZE bf16 == out bytes exactly

    k_prep<<<512, 256, 0, stream>>>(x, Tarena, Ht);
    k_prep_A<<<dim3(32, 32, 3), 256, 0, stream>>>(A0, A1, A2, AT);
    k_prep_W<<<56, 256, 0, stream>>>(W, Wb);
    // hop1: X = x-T -> h1-T (Ht cc0 = 32+64z) + [n2,v] copies for hop2
    k_gemm<<<dim3(104, 8, 3), 256, 0, stream>>>(Tarena, 0L, AT,
                                                Tarena + SZE, (long)SZE, Ht, 32, 1);
    // hop2: X = h1-T -> Ht blocks (cc0 = 64+64z), no T write
    k_gemm<<<dim3(104, 8, 3), 256, 0, stream>>>(Tarena + SZE, (long)SZE, AT,
                                                nullptr, 0L, Ht, 64, 0);
    k_fc<<<2048, 256, 0, stream>>>(Ht, Wb, bias, (float*)d_out);
}